// Round 13
// baseline (283.960 us; speedup 1.0000x reference)
//
#include <hip/hip_runtime.h>
#include <hip/hip_bf16.h>

// ---------------------------------------------------------------------------
// QuantizedLinear: out[M,N] = (x[M,K] @ (Wq[N,K]*s[N,1]).T) + b[N]
// INT8 path (R6+, absmax 7.0): w -> i8 exact, x -> i8 per-row quant,
// epilogue acc*sx[m]*s[n]+b.
// Round 13: R12 skeleton (BK=128, 256x256, 8 waves 2Mx4N, dbuf-2, 2-phase/
// 2-barrier, verified 0-conflict swizzle) with mfma_i32_32x32x32_i8
// (4404 vs 3944 TOPS, half the instructions, same LDS bytes).
// Frag maps: A/B row=lane&31, k=(lane>>5)*16+[0..16) per K-step (analog of
// validated 16x16x64 map); C/D col=lane&31, row=(reg&3)+8*(reg>>2)+4*(lane>>5).
// ---------------------------------------------------------------------------

typedef __attribute__((ext_vector_type(4)))  int   i32x4;
typedef __attribute__((ext_vector_type(16))) int   i32x16;
typedef __attribute__((ext_vector_type(4)))  float f32x4;
typedef __attribute__((ext_vector_type(4)))  unsigned int u32x4;

// ---- w: fp32 (integer-valued) -> i8, exact ---------------------------------
__device__ static inline unsigned int pack4(int q0, int q1, int q2, int q3) {
    return (unsigned)(q0 & 255) | ((unsigned)(q1 & 255) << 8) |
           ((unsigned)(q2 & 255) << 16) | ((unsigned)(q3 & 255) << 24);
}

__global__ void w_to_i8(const float* __restrict__ in,
                        u32x4* __restrict__ out, long n16) {
    const long stride = (long)gridDim.x * blockDim.x;
    for (long i = (long)blockIdx.x * blockDim.x + threadIdx.x; i < n16; i += stride) {
        const f32x4* p = reinterpret_cast<const f32x4*>(in) + i * 4;
        u32x4 o;
#pragma unroll
        for (int v = 0; v < 4; ++v) {
            f32x4 f = p[v];
            o[v] = pack4(__float2int_rn(f[0]), __float2int_rn(f[1]),
                         __float2int_rn(f[2]), __float2int_rn(f[3]));
        }
        out[i] = o;
    }
}

// ---- x: per-row absmax quant to i8; sx[row] = rowmax/127 -------------------
__global__ void x_quant_i8(const float* __restrict__ x,
                           unsigned int* __restrict__ xq,
                           float* __restrict__ sx, int K) {
    const int row = blockIdx.x;
    const int tid = threadIdx.x;
    const float* xr = x + (size_t)row * K;
    float m = 0.f;
    for (int b = tid * 16; b < K; b += blockDim.x * 16) {
        const f32x4* p = (const f32x4*)(xr + b);
#pragma unroll
        for (int v = 0; v < 4; ++v) {
            f32x4 f = p[v];
            m = fmaxf(m, fmaxf(fmaxf(fabsf(f[0]), fabsf(f[1])),
                               fmaxf(fabsf(f[2]), fabsf(f[3]))));
        }
    }
#pragma unroll
    for (int off = 32; off; off >>= 1) m = fmaxf(m, __shfl_xor(m, off));
    __shared__ float red[8];
    if ((tid & 63) == 0) red[tid >> 6] = m;
    __syncthreads();
    const int nw = blockDim.x >> 6;
    m = red[0];
    for (int i = 1; i < nw; ++i) m = fmaxf(m, red[i]);
    const float inv = (m > 0.f) ? 127.0f / m : 0.f;
    if (tid == 0) sx[row] = m * (1.0f / 127.0f);
    for (int b = tid * 16; b < K; b += blockDim.x * 16) {
        const f32x4* p = (const f32x4*)(xr + b);
        u32x4 o;
#pragma unroll
        for (int v = 0; v < 4; ++v) {
            f32x4 f = p[v];
            int q0 = min(127, max(-127, __float2int_rn(f[0] * inv)));
            int q1 = min(127, max(-127, __float2int_rn(f[1] * inv)));
            int q2 = min(127, max(-127, __float2int_rn(f[2] * inv)));
            int q3 = min(127, max(-127, __float2int_rn(f[3] * inv)));
            o[v] = pack4(q0, q1, q2, q3);
        }
        *reinterpret_cast<u32x4*>((char*)xq + (size_t)row * K + b) = o;
    }
}

// ---------------------------------------------------------------------------
// i8 GEMM, BK=128, 32x32x32 MFMA. LDS: A rings r*32768 (2 halves of 16 KiB);
// B rings 65536 + r*32768. A-half h = tile rows bit6==h (local row =
// ((rl>>6)<<7 folded): wr slab -> local wr*64 + [0,64)); B-half h = rows
// bit5==h (local = wc*32 + [0,32) for n-frag h).
// Per wave: 4 M-frags (32 rows) x 2 N-frags (32 cols); acc[4][2] i32x16.
// PhA{stage A1B1(t+1) | rd m0,m1 (8) + n0,n1 (8) | lgkm0 | 16 MFMA | BAR}
// PhB{stage A0B0(t+2) | rd m2,m3 (8) | lgkm0 | 16 MFMA | vm(4) | BAR}
// Swizzle: phys chunk = logical ^ (row&7); pre-swizzled global source,
// linear LDS dest (rule #21). 2 lanes/chunk per quarter-wave -> free.
// ---------------------------------------------------------------------------

#define GLOAD16(src, dst) __builtin_amdgcn_global_load_lds( \
    (const __attribute__((address_space(1))) void*)(src),   \
    (__attribute__((address_space(3))) void*)(dst), 16, 0, 0)

#define FENCE() asm volatile("" ::: "memory")
#define BAR()  do { FENCE(); __builtin_amdgcn_s_barrier(); FENCE(); } while (0)
#define WAIT_VM(n) asm volatile("s_waitcnt vmcnt(" #n ")" ::: "memory")
#define WAIT_LGKM0() asm volatile("s_waitcnt lgkmcnt(0)" ::: "memory")
#define SCHED0() __builtin_amdgcn_sched_barrier(0)

__global__ __launch_bounds__(512, 2)
void qlinear_gemm_i8x32(const char* __restrict__ A,   // [M,K] i8
                        const char* __restrict__ B,   // [N,K] i8
                        const float* __restrict__ sx, // [M]
                        const float* __restrict__ scales,  // [N]
                        const float* __restrict__ bias,    // [N]
                        float* __restrict__ C,             // [M,N] f32
                        int M, int N, int K, int nbx) {
    __shared__ __align__(128) char smem[131072];

    const int tid  = threadIdx.x;
    const int lane = tid & 63;
    const int wid  = tid >> 6;
    const int wr   = wid >> 2;   // 0..1 -> 128-row slab
    const int wc   = wid & 3;    // 0..3 -> 64-col slab

    // T1: bijective XCD swizzle (m204)
    const int nwg = gridDim.x;
    const int q = nwg >> 3, r = nwg & 7;
    const int xcd = blockIdx.x & 7, boff_ = blockIdx.x >> 3;
    const int swz = (xcd < r ? xcd * (q + 1) : r * (q + 1) + (xcd - r) * q) + boff_;
    const int bcol = swz % nbx;
    const int brow = swz / nbx;

    const char* Ag = A + (size_t)brow * 256 * K;
    const char* Bg = B + (size_t)bcol * 256 * K;

    // ---- staging source offsets (identical to R11/R12) ----
    size_t sA[2], sB[2];
#pragma unroll
    for (int g = 0; g < 2; ++g) {
        const int c = tid + g * 512, rl = c >> 3, j = c & 7;
        const int rowA = ((rl >> 6) << 7) + (rl & 63);   // + h*64 at use
        const int rowB = ((rl >> 5) << 6) + (rl & 31);   // + h*32 at use
        sA[g] = (size_t)rowA * K + ((j ^ (rl & 7)) << 4);
        sB[g] = (size_t)rowB * K + ((j ^ (rl & 7)) << 4);
    }
    const int ld0 = tid * 16;

    auto stageA = [&](int rg, int h, int t) {
        const char* G = Ag + (size_t)h * 64 * K + (size_t)t * 128;
        char* base = smem + rg * 32768 + h * 16384;
        GLOAD16(G + sA[0], base + ld0);
        GLOAD16(G + sA[1], base + ld0 + 8192);
    };
    auto stageB = [&](int rg, int h, int t) {
        const char* G = Bg + (size_t)h * 32 * K + (size_t)t * 128;
        char* base = smem + 65536 + rg * 32768 + h * 16384;
        GLOAD16(G + sB[0], base + ld0);
        GLOAD16(G + sB[1], base + ld0 + 8192);
    };

    // ---- read geometry (32x32 frags) ----
    const int l31 = lane & 31;
    const int lhi = lane >> 5;            // k-chunk within K-step
    const int l7  = lane & 7;             // == local_row & 7 for all frags
    // phys chunk offsets for ksteps 0..3
    int pk[4];
#pragma unroll
    for (int ks = 0; ks < 4; ++ks) pk[ks] = ((ks * 2 + lhi) ^ l7) << 4;

    i32x16 acc[4][2] = {};                // [m-frag][n-frag]
    i32x4 am0[4], am1[4], am2[4], am3[4]; // A frags x kstep
    i32x4 bn0[4], bn1[4];                 // B frags x kstep

    auto rdA32 = [&](int rg, int mh, int j, i32x4 (&d)[4]) {  // 4 b128
        const char* p = smem + rg * 32768 + mh * 16384 +
                        (wr * 64 + j * 32 + l31) * 128;
#pragma unroll
        for (int ks = 0; ks < 4; ++ks) d[ks] = *(const i32x4*)(p + pk[ks]);
    };
    auto rdB32 = [&](int rg, int n, i32x4 (&d)[4]) {          // 4 b128
        const char* p = smem + 65536 + rg * 32768 + n * 16384 +
                        (wc * 32 + l31) * 128;
#pragma unroll
        for (int ks = 0; ks < 4; ++ks) d[ks] = *(const i32x4*)(p + pk[ks]);
    };
    // one phase: 2 A-frags x 2 B-frags x 4 ksteps = 16 MFMA, ks outer
    auto mfmaPh = [&](const i32x4 (&x0)[4], const i32x4 (&x1)[4], int mbase) {
        __builtin_amdgcn_s_setprio(1);
#pragma unroll
        for (int ks = 0; ks < 4; ++ks) {
            acc[mbase][0]     = __builtin_amdgcn_mfma_i32_32x32x32_i8(x0[ks], bn0[ks], acc[mbase][0], 0, 0, 0);
            acc[mbase][1]     = __builtin_amdgcn_mfma_i32_32x32x32_i8(x0[ks], bn1[ks], acc[mbase][1], 0, 0, 0);
            acc[mbase + 1][0] = __builtin_amdgcn_mfma_i32_32x32x32_i8(x1[ks], bn0[ks], acc[mbase + 1][0], 0, 0, 0);
            acc[mbase + 1][1] = __builtin_amdgcn_mfma_i32_32x32x32_i8(x1[ks], bn1[ks], acc[mbase + 1][1], 0, 0, 0);
        }
        __builtin_amdgcn_s_setprio(0);
    };

    const int NT = K / 128;   // >= 3 (dispatch guard)

    // ---- prologue: t0 all 4 halves (8 gloads); t1 A0,B0 (4). ----
    stageA(0, 0, 0); stageB(0, 0, 0); stageA(0, 1, 0); stageB(0, 1, 0);
    stageA(1, 0, 1); stageB(1, 0, 1);
    WAIT_VM(4); BAR();

    // ---- main loop: 2 phases, 2 barriers per K-tile ----
    for (int t = 0; t < NT - 2; ++t) {
        const int c = t & 1, o = c ^ 1;
        // PhA: stage t+1:{A1,B1} | rd m0,m1,n0,n1 | MFMA m0,m1 x n0,n1
        stageA(o, 1, t + 1); stageB(o, 1, t + 1);          // in flight: 8
        rdA32(c, 0, 0, am0); rdA32(c, 0, 1, am1);
        rdB32(c, 0, bn0);    rdB32(c, 1, bn1);
        WAIT_LGKM0(); SCHED0();
        mfmaPh(am0, am1, 0);
        BAR();
        // PhB: stage t+2:{A0,B0} | rd m2,m3 | MFMA m2,m3 x n0,n1 | vm(4)
        stageA(c, 0, t + 2); stageB(c, 0, t + 2);          // in flight: 12
        rdA32(c, 1, 0, am2); rdA32(c, 1, 1, am3);
        WAIT_LGKM0(); SCHED0();
        mfmaPh(am2, am3, 2);
        WAIT_VM(4);        // retire tile t+1's 8 gloads; keep t+2:{A0,B0}
        BAR();
    }
    // ---- t = NT-2 ----
    {
        const int c = (NT - 2) & 1, o = c ^ 1;
        stageA(o, 1, NT - 1); stageB(o, 1, NT - 1);        // in flight: 8
        rdA32(c, 0, 0, am0); rdA32(c, 0, 1, am1);
        rdB32(c, 0, bn0);    rdB32(c, 1, bn1);
        WAIT_LGKM0(); SCHED0();
        mfmaPh(am0, am1, 0);
        BAR();
        rdA32(c, 1, 0, am2); rdA32(c, 1, 1, am3);
        WAIT_LGKM0(); SCHED0();
        mfmaPh(am2, am3, 2);
        WAIT_VM(0);        // tile NT-1 landed
        BAR();
    }
    // ---- t = NT-1: pure compute ----
    {
        const int c = (NT - 1) & 1;
        rdA32(c, 0, 0, am0); rdA32(c, 0, 1, am1);
        rdB32(c, 0, bn0);    rdB32(c, 1, bn1);
        WAIT_LGKM0(); SCHED0();
        mfmaPh(am0, am1, 0);
        rdA32(c, 1, 0, am2); rdA32(c, 1, 1, am3);
        WAIT_LGKM0(); SCHED0();
        mfmaPh(am2, am3, 2);
    }

    // ---- epilogue: 32x32 C/D: col = lane&31, row = (reg&3)+8*(reg>>2)+4*(lane>>5)
    const int rofs = (lane >> 5) * 4;
#pragma unroll
    for (int n = 0; n < 2; ++n) {
        const int col = bcol * 256 + wc * 64 + n * 32 + l31;
        const float s  = scales[col];
        const float bz = bias[col];
#pragma unroll
        for (int m = 0; m < 4; ++m) {
            const int rbase = brow * 256 + wr * 128 + m * 32 + rofs;
#pragma unroll
            for (int g = 0; g < 4; ++g) {
                const int rowg = rbase + g * 8;
                const f32x4 sxv = *(const f32x4*)&sx[rowg];
#pragma unroll
                for (int qq = 0; qq < 4; ++qq) {
                    C[(size_t)(rowg + qq) * N + col] =
                        fmaf((float)acc[m][n][g * 4 + qq], sxv[qq] * s, bz);
                }
            }
        }
    }
}

// ---- Fallback: plain fp32 tiled GEMM, correctness insurance ----------------
__global__ void qlinear_fallback(const float* __restrict__ A,
                                 const float* __restrict__ B,
                                 const float* __restrict__ scales,
                                 const float* __restrict__ bias,
                                 float* __restrict__ C, int M, int N, int K) {
    __shared__ float As[16][17], Bs[16][17];
    const int tx = threadIdx.x, ty = threadIdx.y;
    const int row = blockIdx.y * 16 + ty;
    const int col = blockIdx.x * 16 + tx;
    float acc = 0.f;
    for (int k0 = 0; k0 < K; k0 += 16) {
        As[ty][tx] = A[(long)row * K + k0 + tx];
        Bs[ty][tx] = B[(long)(blockIdx.x * 16 + ty) * K + k0 + tx];
        __syncthreads();
#pragma unroll
        for (int kk = 0; kk < 16; ++kk) acc += As[ty][kk] * Bs[tx][kk];
        __syncthreads();
    }
    C[(long)row * N + col] = fmaf(acc, scales[col], bias[col]);
}

extern "C" void kernel_launch(void* const* d_in, const int* in_sizes, int n_in,
                              void* d_out, int out_size, void* d_ws, size_t ws_size,
                              hipStream_t stream) {
    const float* x      = (const float*)d_in[0];
    const float* w      = (const float*)d_in[1];
    const float* scales = (const float*)d_in[2];
    const float* bias   = (const float*)d_in[3];
    float* out = (float*)d_out;

    const int N = in_sizes[2];                  // 11008
    const int K = (int)((long)in_sizes[1] / N); // 4096
    const int M = (int)((long)in_sizes[0] / K); // 4096

    const size_t need = (size_t)M * K + (size_t)N * K + (size_t)M * 4;
    const bool ok = (ws_size >= need) && (M % 256) == 0 && (N % 256) == 0 &&
                    (K % 128) == 0 && (K / 128) >= 3 && (K % 16) == 0;

    if (ok) {
        char* xq = (char*)d_ws;
        char* wq = xq + (size_t)M * K;
        float* sxbuf = (float*)(wq + (size_t)N * K);

        x_quant_i8<<<M, 256, 0, stream>>>(x, (unsigned int*)xq, sxbuf, K);
        w_to_i8<<<2048, 256, 0, stream>>>(w, (u32x4*)wq, (long)N * K / 16);

        const int nbx = N / 256;
        const int nwg = (M / 256) * nbx;
        qlinear_gemm_i8x32<<<nwg, 512, 0, stream>>>(xq, wq, sxbuf, scales, bias,
                                                    out, M, N, K, nbx);
    } else {
        dim3 grid(N / 16, M / 16), blk(16, 16);
        qlinear_fallback<<<grid, blk, 0, stream>>>(x, w, scales, bias, out, M, N, K);
    }
}

// Round 14
// 254.480 us; speedup vs baseline: 1.1158x; 1.1158x over previous
//
#include <hip/hip_runtime.h>
#include <hip/hip_bf16.h>

// ---------------------------------------------------------------------------
// QuantizedLinear: out[M,N] = (x[M,K] @ (Wq[N,K]*s[N,1]).T) + b[N]
// INT8 path (R6+, absmax 7.0): w -> i8 exact, x -> i8 per-row quant,
// mfma_i32_16x16x64_i8, epilogue acc*sx[m]*s[n]+b.
// Round 14: REVERT to R12 (measured optimum: GEMM 196 us, 0 conflicts).
// R13's 32x32 shape hit a structural 4-way bank conflict (32 rows x 8 chunk
// positions, bank-aligned 128B rows) costing more than its +12% MFMA rate.
// Six schedule variants (R6-R13) bracket 196-225 us under the law
// T ~= MFMA + LDS - ~10% overlap; R12's 2-phase/2-barrier BK=128 is best.
// ---------------------------------------------------------------------------

typedef __attribute__((ext_vector_type(4))) int   i32x4;
typedef __attribute__((ext_vector_type(4))) float f32x4;
typedef __attribute__((ext_vector_type(4))) unsigned int u32x4;

// ---- w: fp32 (integer-valued) -> i8, exact ---------------------------------
__device__ static inline unsigned int pack4(int q0, int q1, int q2, int q3) {
    return (unsigned)(q0 & 255) | ((unsigned)(q1 & 255) << 8) |
           ((unsigned)(q2 & 255) << 16) | ((unsigned)(q3 & 255) << 24);
}

__global__ void w_to_i8(const float* __restrict__ in,
                        u32x4* __restrict__ out, long n16) {
    const long stride = (long)gridDim.x * blockDim.x;
    for (long i = (long)blockIdx.x * blockDim.x + threadIdx.x; i < n16; i += stride) {
        const f32x4* p = reinterpret_cast<const f32x4*>(in) + i * 4;
        u32x4 o;
#pragma unroll
        for (int v = 0; v < 4; ++v) {
            f32x4 f = p[v];
            o[v] = pack4(__float2int_rn(f[0]), __float2int_rn(f[1]),
                         __float2int_rn(f[2]), __float2int_rn(f[3]));
        }
        out[i] = o;
    }
}

// ---- x: per-row absmax quant to i8; sx[row] = rowmax/127 -------------------
__global__ void x_quant_i8(const float* __restrict__ x,
                           unsigned int* __restrict__ xq,
                           float* __restrict__ sx, int K) {
    const int row = blockIdx.x;
    const int tid = threadIdx.x;
    const float* xr = x + (size_t)row * K;
    float m = 0.f;
    for (int b = tid * 16; b < K; b += blockDim.x * 16) {
        const f32x4* p = (const f32x4*)(xr + b);
#pragma unroll
        for (int v = 0; v < 4; ++v) {
            f32x4 f = p[v];
            m = fmaxf(m, fmaxf(fmaxf(fabsf(f[0]), fabsf(f[1])),
                               fmaxf(fabsf(f[2]), fabsf(f[3]))));
        }
    }
#pragma unroll
    for (int off = 32; off; off >>= 1) m = fmaxf(m, __shfl_xor(m, off));
    __shared__ float red[8];
    if ((tid & 63) == 0) red[tid >> 6] = m;
    __syncthreads();
    const int nw = blockDim.x >> 6;
    m = red[0];
    for (int i = 1; i < nw; ++i) m = fmaxf(m, red[i]);
    const float inv = (m > 0.f) ? 127.0f / m : 0.f;
    if (tid == 0) sx[row] = m * (1.0f / 127.0f);
    for (int b = tid * 16; b < K; b += blockDim.x * 16) {
        const f32x4* p = (const f32x4*)(xr + b);
        u32x4 o;
#pragma unroll
        for (int v = 0; v < 4; ++v) {
            f32x4 f = p[v];
            int q0 = min(127, max(-127, __float2int_rn(f[0] * inv)));
            int q1 = min(127, max(-127, __float2int_rn(f[1] * inv)));
            int q2 = min(127, max(-127, __float2int_rn(f[2] * inv)));
            int q3 = min(127, max(-127, __float2int_rn(f[3] * inv)));
            o[v] = pack4(q0, q1, q2, q3);
        }
        *reinterpret_cast<u32x4*>((char*)xq + (size_t)row * K + b) = o;
    }
}

// ---------------------------------------------------------------------------
// i8 GEMM, BK=128. LDS: A rings r*32768 (2 halves of 16 KiB); B rings
// 65536 + r*32768. A-half h = tile rows bit6==h; B-half h = rows bit5==h.
// Swizzle (R4/R11, 0 conflicts): phys chunk = logical ^ (row&7); pre-swizzled
// global source, linear LDS dest (rule #21).
// PhA{stage A1B1(t+1) | rd a0,b0,b1 | lgkm0 | 32 MFMA | BAR}
// PhB{stage A0B0(t+2) | rd a1 | lgkm0 | 32 MFMA | vm(4) | BAR}
// ---------------------------------------------------------------------------

#define GLOAD16(src, dst) __builtin_amdgcn_global_load_lds( \
    (const __attribute__((address_space(1))) void*)(src),   \
    (__attribute__((address_space(3))) void*)(dst), 16, 0, 0)

#define FENCE() asm volatile("" ::: "memory")
#define BAR()  do { FENCE(); __builtin_amdgcn_s_barrier(); FENCE(); } while (0)
#define WAIT_VM(n) asm volatile("s_waitcnt vmcnt(" #n ")" ::: "memory")
#define WAIT_LGKM0() asm volatile("s_waitcnt lgkmcnt(0)" ::: "memory")
#define SCHED0() __builtin_amdgcn_sched_barrier(0)

__global__ __launch_bounds__(512, 2)
void qlinear_gemm_i8v2(const char* __restrict__ A,   // [M,K] i8
                       const char* __restrict__ B,   // [N,K] i8
                       const float* __restrict__ sx, // [M]
                       const float* __restrict__ scales,  // [N]
                       const float* __restrict__ bias,    // [N]
                       float* __restrict__ C,             // [M,N] f32
                       int M, int N, int K, int nbx) {
    __shared__ __align__(128) char smem[131072];

    const int tid  = threadIdx.x;
    const int lane = tid & 63;
    const int wid  = tid >> 6;
    const int wr   = wid >> 2;   // 0..1 -> 128-row slab
    const int wc   = wid & 3;    // 0..3 -> 64-col slab

    // T1: bijective XCD swizzle (m204)
    const int nwg = gridDim.x;
    const int q = nwg >> 3, r = nwg & 7;
    const int xcd = blockIdx.x & 7, boff_ = blockIdx.x >> 3;
    const int swz = (xcd < r ? xcd * (q + 1) : r * (q + 1) + (xcd - r) * q) + boff_;
    const int bcol = swz % nbx;
    const int brow = swz / nbx;

    const char* Ag = A + (size_t)brow * 256 * K;
    const char* Bg = B + (size_t)bcol * 256 * K;

    // ---- staging source offsets (h-independent parts), 2 chunks/thread ----
    size_t sA[2], sB[2];
#pragma unroll
    for (int g = 0; g < 2; ++g) {
        const int c = tid + g * 512, rl = c >> 3, j = c & 7;
        const int rowA = ((rl >> 6) << 7) + (rl & 63);   // + h*64 at use
        const int rowB = ((rl >> 5) << 6) + (rl & 31);   // + h*32 at use
        sA[g] = (size_t)rowA * K + ((j ^ (rl & 7)) << 4);
        sB[g] = (size_t)rowB * K + ((j ^ (rl & 7)) << 4);
    }
    const int ld0 = tid * 16;

    auto stageA = [&](int rg, int h, int t) {
        const char* G = Ag + (size_t)h * 64 * K + (size_t)t * 128;
        char* base = smem + rg * 32768 + h * 16384;
        GLOAD16(G + sA[0], base + ld0);
        GLOAD16(G + sA[1], base + ld0 + 8192);
    };
    auto stageB = [&](int rg, int h, int t) {
        const char* G = Bg + (size_t)h * 32 * K + (size_t)t * 128;
        char* base = smem + 65536 + rg * 32768 + h * 16384;
        GLOAD16(G + sB[0], base + ld0);
        GLOAD16(G + sB[1], base + ld0 + 8192);
    };

    // ---- read geometry ----
    const int px0 = (((lane >> 4) ^ (lane & 7)) << 4);        // kk=0
    const int px1 = (((4 + (lane >> 4)) ^ (lane & 7)) << 4);  // kk=1
    const int arow = (wr * 64 + (lane & 15)) * 128;
    const int brw  = (wc * 32 + (lane & 15)) * 128;

    i32x4 acc[8][4] = {};
    i32x4 a0[8], a1[8], b0[4], b1[4];

    auto rdA = [&](int rg, int mh, i32x4 (&d)[8]) {   // 8 ds_read_b128
        const char* p = smem + rg * 32768 + mh * 16384 + arow;
#pragma unroll
        for (int i = 0; i < 4; ++i) {
            d[i * 2]     = *(const i32x4*)(p + i * 2048 + px0);
            d[i * 2 + 1] = *(const i32x4*)(p + i * 2048 + px1);
        }
    };
    auto rdB = [&](int rg, int nh, i32x4 (&d)[4]) {   // 4 ds_read_b128
        const char* p = smem + 65536 + rg * 32768 + nh * 16384 + brw;
#pragma unroll
        for (int n = 0; n < 2; ++n) {
            d[n * 2]     = *(const i32x4*)(p + n * 2048 + px0);
            d[n * 2 + 1] = *(const i32x4*)(p + n * 2048 + px1);
        }
    };
    auto mfma16 = [&](const i32x4 (&a)[8], const i32x4 (&b)[4], int mh, int nh) {
#pragma unroll
        for (int i = 0; i < 4; ++i)
#pragma unroll
            for (int n = 0; n < 2; ++n) {
                i32x4& ac = acc[mh * 4 + i][nh * 2 + n];
                ac = __builtin_amdgcn_mfma_i32_16x16x64_i8(a[i * 2], b[n * 2], ac, 0, 0, 0);
                ac = __builtin_amdgcn_mfma_i32_16x16x64_i8(a[i * 2 + 1], b[n * 2 + 1], ac, 0, 0, 0);
            }
    };

    const int NT = K / 128;   // >= 3 (dispatch guard)

    // ---- prologue: t0 all 4 halves (8 gloads); t1 A0,B0 (4). vm(4) -> t0
    // landed, t1:{A0,B0} in flight = loop invariant. ----
    stageA(0, 0, 0); stageB(0, 0, 0); stageA(0, 1, 0); stageB(0, 1, 0);
    stageA(1, 0, 1); stageB(1, 0, 1);
    WAIT_VM(4); BAR();

    // ---- main loop: 2 phases, 2 barriers per K-tile ----
    for (int t = 0; t < NT - 2; ++t) {
        const int c = t & 1, o = c ^ 1;
        // PhA: stage t+1:{A1,B1} | read a0,b0,b1 | MFMA q(0,0),(0,1)
        stageA(o, 1, t + 1); stageB(o, 1, t + 1);          // in flight: 8
        rdA(c, 0, a0); rdB(c, 0, b0); rdB(c, 1, b1);
        WAIT_LGKM0(); SCHED0();
        __builtin_amdgcn_s_setprio(1);
        mfma16(a0, b0, 0, 0);
        mfma16(a0, b1, 0, 1);
        __builtin_amdgcn_s_setprio(0);
        BAR();
        // PhB: stage t+2:{A0,B0} | read a1 | MFMA q(1,0),(1,1) | vm(4)
        stageA(c, 0, t + 2); stageB(c, 0, t + 2);          // in flight: 12
        rdA(c, 1, a1);
        WAIT_LGKM0(); SCHED0();
        __builtin_amdgcn_s_setprio(1);
        mfma16(a1, b0, 1, 0);
        mfma16(a1, b1, 1, 1);
        __builtin_amdgcn_s_setprio(0);
        WAIT_VM(4);        // retire tile t+1's 8 gloads; keep t+2:{A0,B0}
        BAR();
    }
    // ---- t = NT-2: PhA stages last halves of NT-1; PhB drains ----
    {
        const int c = (NT - 2) & 1, o = c ^ 1;
        stageA(o, 1, NT - 1); stageB(o, 1, NT - 1);        // in flight: 8
        rdA(c, 0, a0); rdB(c, 0, b0); rdB(c, 1, b1);
        WAIT_LGKM0(); SCHED0();
        __builtin_amdgcn_s_setprio(1);
        mfma16(a0, b0, 0, 0);
        mfma16(a0, b1, 0, 1);
        __builtin_amdgcn_s_setprio(0);
        BAR();
        rdA(c, 1, a1);
        WAIT_LGKM0(); SCHED0();
        __builtin_amdgcn_s_setprio(1);
        mfma16(a1, b0, 1, 0);
        mfma16(a1, b1, 1, 1);
        __builtin_amdgcn_s_setprio(0);
        WAIT_VM(0);        // tile NT-1 landed
        BAR();
    }
    // ---- t = NT-1: pure compute ----
    {
        const int c = (NT - 1) & 1;
        rdA(c, 0, a0); rdB(c, 0, b0); rdB(c, 1, b1);
        WAIT_LGKM0(); SCHED0();
        mfma16(a0, b0, 0, 0);
        mfma16(a0, b1, 0, 1);
        rdA(c, 1, a1);
        WAIT_LGKM0(); SCHED0();
        mfma16(a1, b0, 1, 0);
        mfma16(a1, b1, 1, 1);
    }

    // ---- epilogue: row = wr*128+(mi>>2)*64+(mi&3)*16+(lane>>4)*4+j
    //                col = wc*64 +(ni>>1)*32+(ni&1)*16+(lane&15)
    const int lc  = lane & 15;
    const int lr4 = (lane >> 4) * 4;
    float sarr[4], barr[4];
#pragma unroll
    for (int ni = 0; ni < 4; ++ni) {
        const int n = bcol * 256 + wc * 64 + (ni >> 1) * 32 + (ni & 1) * 16 + lc;
        sarr[ni] = scales[n];
        barr[ni] = bias[n];
    }
#pragma unroll
    for (int mi = 0; mi < 8; ++mi) {
        const int mb = brow * 256 + wr * 128 + (mi >> 2) * 64 + (mi & 3) * 16 + lr4;
#pragma unroll
        for (int j = 0; j < 4; ++j) {
            const size_t rowoff = (size_t)(mb + j) * N;
            const float sm = sx[mb + j];
#pragma unroll
            for (int ni = 0; ni < 4; ++ni) {
                const int n = bcol * 256 + wc * 64 + (ni >> 1) * 32 + (ni & 1) * 16 + lc;
                C[rowoff + n] = fmaf((float)acc[mi][ni][j], sm * sarr[ni], barr[ni]);
            }
        }
    }
}

// ---- Fallback: plain fp32 tiled GEMM, correctness insurance ----------------
__global__ void qlinear_fallback(const float* __restrict__ A,
                                 const float* __restrict__ B,
                                 const float* __restrict__ scales,
                                 const float* __restrict__ bias,
                                 float* __restrict__ C, int M, int N, int K) {
    __shared__ float As[16][17], Bs[16][17];
    const int tx = threadIdx.x, ty = threadIdx.y;
    const int row = blockIdx.y * 16 + ty;
    const int col = blockIdx.x * 16 + tx;
    float acc = 0.f;
    for (int k0 = 0; k0 < K; k0 += 16) {
        As[ty][tx] = A[(long)row * K + k0 + tx];
        Bs[ty][tx] = B[(long)(blockIdx.x * 16 + ty) * K + k0 + tx];
        __syncthreads();
#pragma unroll
        for (int kk = 0; kk < 16; ++kk) acc += As[ty][kk] * Bs[tx][kk];
        __syncthreads();
    }
    C[(long)row * N + col] = fmaf(acc, scales[col], bias[col]);
}

extern "C" void kernel_launch(void* const* d_in, const int* in_sizes, int n_in,
                              void* d_out, int out_size, void* d_ws, size_t ws_size,
                              hipStream_t stream) {
    const float* x      = (const float*)d_in[0];
    const float* w      = (const float*)d_in[1];
    const float* scales = (const float*)d_in[2];
    const float* bias   = (const float*)d_in[3];
    float* out = (float*)d_out;

    const int N = in_sizes[2];                  // 11008
    const int K = (int)((long)in_sizes[1] / N); // 4096
    const int M = (int)((long)in_sizes[0] / K); // 4096

    const size_t need = (size_t)M * K + (size_t)N * K + (size_t)M * 4;
    const bool ok = (ws_size >= need) && (M % 256) == 0 && (N % 256) == 0 &&
                    (K % 128) == 0 && (K / 128) >= 3 && (K % 16) == 0;

    if (ok) {
        char* xq = (char*)d_ws;
        char* wq = xq + (size_t)M * K;
        float* sxbuf = (float*)(wq + (size_t)N * K);

        x_quant_i8<<<M, 256, 0, stream>>>(x, (unsigned int*)xq, sxbuf, K);
        w_to_i8<<<2048, 256, 0, stream>>>(w, (u32x4*)wq, (long)N * K / 16);

        const int nbx = N / 256;
        const int nwg = (M / 256) * nbx;
        qlinear_gemm_i8v2<<<nwg, 512, 0, stream>>>(xq, wq, sxbuf, scales, bias,
                                                   out, M, N, K, nbx);
    } else {
        dim3 grid(N / 16, M / 16), blk(16, 16);
        qlinear_fallback<<<grid, blk, 0, stream>>>(x, w, scales, bias, out, M, N, K);
    }
}